// Round 1
// baseline (266.884 us; speedup 1.0000x reference)
//
#include <hip/hip_runtime.h>
#include <math.h>

// DifferentiableSoftmaxTree: hierarchical (binary-tree) softmax NLL.
// BATCH=4096, FDIM=512, DEPTH=16, NUM_INTERNAL=49999.
//
// Restructured (v2): one 64-lane wave per batch element, but the 16 path
// nodes are distributed ACROSS lanes (node k = lane>>2, quad member
// q = lane&3) instead of iterated in time. Each lane streams 128 feature
// dims x 2 columns for its node as immediate-offset dwordx4 loads.
// Cross-lane ops per wave: 8 (was 192); softplus chains: 1 (was 16).
// Same bytes, same FLOPs -- removes the serialized per-node
// butterfly+softplus critical path that made the old kernel
// latency-bound well above the ~10us L1/L2 streaming floor.

constexpr int BATCH = 4096;
constexpr int FDIM  = 512;
constexpr int DEPTH = 16;

__global__ __launch_bounds__(256) void hstree_loss(
    const float* __restrict__ features,
    const int*   __restrict__ targets,
    const float* __restrict__ node_weights,
    const int*   __restrict__ path_nodes,
    const int*   __restrict__ path_dirs,
    float*       __restrict__ out)
{
    const int lane = threadIdx.x & 63;
    const int b    = (blockIdx.x << 2) + (threadIdx.x >> 6);

    const int k = lane >> 2;  // node slot 0..15 (tree level)
    const int q = lane & 3;   // quad member: dims [16j+4q .. 16j+4q+3]

    // target is wave-uniform -> SGPR
    const int t = __builtin_amdgcn_readfirstlane(targets[b]);

    const int node = path_nodes[t * DEPTH + k];
    const int dir  = path_dirs [t * DEPTH + k];
    const int n    = node < 0 ? 0 : node;  // padding -> node 0 (L2-hot, masked later)

    // weights [node][d][c]: float4 m = (w[2m][0], w[2m][1], w[2m+1][0], w[2m+1][1])
    const float4* __restrict__ wp = (const float4*)(node_weights + (size_t)n * (FDIM * 2)) + 2 * q;
    const float4* __restrict__ fp = (const float4*)(features + (size_t)b * FDIM) + q;

    // two accumulator pairs to break the FMA dependence chain
    float acc0a = 0.f, acc1a = 0.f, acc0b = 0.f, acc1b = 0.f;

    // per j: lane covers dims 16j+4q .. 16j+4q+3 (quad covers 16j..16j+15).
    // All offsets are compile-time -> fold into global_load immediate offsets.
#pragma unroll 4
    for (int j = 0; j < 32; j += 2) {
        const float4 wa0 = wp[8 * j];
        const float4 wb0 = wp[8 * j + 1];
        const float4 f0  = fp[4 * j];
        const float4 wa1 = wp[8 * j + 8];
        const float4 wb1 = wp[8 * j + 9];
        const float4 f1  = fp[4 * j + 4];

        acc0a += f0.x * wa0.x + f0.y * wa0.z + f0.z * wb0.x + f0.w * wb0.z;
        acc1a += f0.x * wa0.y + f0.y * wa0.w + f0.z * wb0.y + f0.w * wb0.w;
        acc0b += f1.x * wa1.x + f1.y * wa1.z + f1.z * wb1.x + f1.w * wb1.z;
        acc1b += f1.x * wa1.y + f1.y * wa1.w + f1.z * wb1.y + f1.w * wb1.w;
    }

    float l0 = acc0a + acc0b;
    float l1 = acc1a + acc1b;

    // reduce across the 4-lane quad (xor 1, 2 stay inside the quad)
    l0 += __shfl_xor(l0, 1, 64);
    l1 += __shfl_xor(l1, 1, 64);
    l0 += __shfl_xor(l0, 2, 64);
    l1 += __shfl_xor(l1, 2, 64);

    // -log_softmax(l)[dir] == softplus(-(l_dir - l_other)), stable form.
    // All 4 quad lanes compute it redundantly (no divergence), masked below.
    const float z  = (dir == 0) ? (l0 - l1) : (l1 - l0);
    const float sp = fmaxf(-z, 0.0f) + log1pf(__expf(-fabsf(z)));

    // keep one copy per node slot, drop padded levels, sum the 16 slots
    float v = (node >= 0 && q == 0) ? sp : 0.0f;
    v += __shfl_xor(v, 4, 64);
    v += __shfl_xor(v, 8, 64);
    v += __shfl_xor(v, 16, 64);
    v += __shfl_xor(v, 32, 64);

    if (lane == 0) out[b] = v;
}

extern "C" void kernel_launch(void* const* d_in, const int* in_sizes, int n_in,
                              void* d_out, int out_size, void* d_ws, size_t ws_size,
                              hipStream_t stream) {
    const float* features     = (const float*)d_in[0];
    const int*   targets      = (const int*)  d_in[1];
    const float* node_weights = (const float*)d_in[2];
    const int*   path_nodes   = (const int*)  d_in[3];
    const int*   path_dirs    = (const int*)  d_in[4];
    float*       out          = (float*)d_out;

    // 4 waves (4 batch rows) per 256-thread block; 1024 blocks
    hstree_loss<<<BATCH / 4, 256, 0, stream>>>(
        features, targets, node_weights, path_nodes, path_dirs, out);
}